// Round 5
// baseline (2340.436 us; speedup 1.0000x reference)
//
#include <hip/hip_runtime.h>
#include <stdint.h>

#define N_NODES 2000
#define N_EDGES 64000
#define EDIM 16
#define ENH 128
#define HD 64
#define T_STEPS 8
#define HH 4096  // HD*HD

typedef unsigned short u16;
typedef __bf16 bf16x8 __attribute__((ext_vector_type(8)));
typedef float float4v __attribute__((ext_vector_type(4)));

// ---- static device scratch (rewritten every call); d_ws holds Aq + x/m ----
__device__ u16   g_h1_hi[(size_t)N_EDGES * ENH];   // 16.4 MB
__device__ u16   g_h1_lo[(size_t)N_EDGES * ENH];   // 16.4 MB
__device__ u16   g_w2t_hi[HH * ENH];               // 1 MB
__device__ u16   g_w2t_lo[HH * ENH];               // 1 MB
__device__ float g_scale[(N_EDGES / 128) * (HH / 128)];  // per-tile decode scale

__device__ __forceinline__ float b2f(u16 h) {
    union { unsigned int u; float f; } v; v.u = ((unsigned int)h) << 16; return v.f;
}
__device__ __forceinline__ u16 f2b(float f) {
    union { float f; unsigned int u; } v; v.f = f;
    unsigned int u = v.u;
    return (u16)((u + 0x7FFFu + ((u >> 16) & 1u)) >> 16);  // RNE
}

// ---- x fp32 -> ping-pong buffer; also zero m for the first step's atomics ----
__global__ void k_xinit(const float* __restrict__ xin, float* __restrict__ x0,
                        float* __restrict__ m) {
    int i = blockIdx.x * 256 + threadIdx.x;
    if (i < N_NODES * HD) { x0[i] = xin[i]; m[i] = 0.f; }
}

// ---- h1 = relu(ef @ W1 + b1) in fp32, stored as exact bf16 hi+lo split ----
__global__ __launch_bounds__(256) void k_h1(const float* __restrict__ edge_data,
                                            const int* __restrict__ edges,
                                            const float* __restrict__ W1,
                                            const float* __restrict__ b1) {
    int tid = threadIdx.x;
    int e = blockIdx.x * 2 + (tid >> 7);
    int c = tid & 127;
    int src = edges[2 * e], tgt = edges[2 * e + 1];
    const float* ef = edge_data + ((size_t)src * N_NODES + (size_t)tgt) * EDIM;
    float acc = b1[c];
#pragma unroll
    for (int k = 0; k < EDIM; k++)
        acc += ef[k] * W1[k * ENH + c];
    float v = fmaxf(acc, 0.f);
    u16 hi = f2b(v);
    size_t idx = (size_t)e * ENH + c;
    g_h1_hi[idx] = hi;
    g_h1_lo[idx] = f2b(v - b2f(hi));
}

// ---- W2 (128 x 4096) -> transposed bf16 hi/lo planes (k-contiguous) ----
__global__ void k_w2t(const float* __restrict__ W2) {
    int idx = blockIdx.x * 256 + threadIdx.x;  // = n*128 + k
    int n = idx >> 7, k = idx & 127;
    float v = W2[(size_t)k * HH + n];
    u16 hi = f2b(v);
    g_w2t_hi[idx] = hi;
    g_w2t_lo[idx] = f2b(v - b2f(hi));
}

// ---- A = relu(h1 @ W2 + b2) in ~fp32 via 3-way split MFMA; quantize each
// 128x128 tile to u16 with per-tile scale. M=64000, N=4096, K=128. ----
__global__ __launch_bounds__(256) void k_gemmA(const float* __restrict__ b2,
                                               u16* __restrict__ Aq) {
    int bid = blockIdx.x;
    int cb = bid & 31;        // col-block fast: consecutive blocks share h1 tile
    int rb = bid >> 5;
    int w = threadIdx.x >> 6, l = threadIdx.x & 63;
    int quad = l >> 4, lr = l & 15;
    int m0 = rb * 128 + w * 32;
    int n0 = cb * 128;

    float4v acc[2][8];
#pragma unroll
    for (int i = 0; i < 2; i++)
#pragma unroll
        for (int j = 0; j < 8; j++) acc[i][j] = (float4v){0.f, 0.f, 0.f, 0.f};

#pragma unroll
    for (int kc = 0; kc < 4; kc++) {
        int ko = kc * 32 + quad * 8;
        bf16x8 ah[2], al[2], bh[8], bl[8];
#pragma unroll
        for (int sr = 0; sr < 2; sr++) {
            size_t base = (size_t)(m0 + sr * 16 + lr) * 128 + ko;
            ah[sr] = *(const bf16x8*)(g_h1_hi + base);
            al[sr] = *(const bf16x8*)(g_h1_lo + base);
        }
#pragma unroll
        for (int sc = 0; sc < 8; sc++) {
            size_t base = (size_t)(n0 + sc * 16 + lr) * 128 + ko;
            bh[sc] = *(const bf16x8*)(g_w2t_hi + base);
            bl[sc] = *(const bf16x8*)(g_w2t_lo + base);
        }
#pragma unroll
        for (int sr = 0; sr < 2; sr++)
#pragma unroll
            for (int sc = 0; sc < 8; sc++) {
                acc[sr][sc] = __builtin_amdgcn_mfma_f32_16x16x32_bf16(
                    ah[sr], bh[sc], acc[sr][sc], 0, 0, 0);
                acc[sr][sc] = __builtin_amdgcn_mfma_f32_16x16x32_bf16(
                    ah[sr], bl[sc], acc[sr][sc], 0, 0, 0);
                acc[sr][sc] = __builtin_amdgcn_mfma_f32_16x16x32_bf16(
                    al[sr], bh[sc], acc[sr][sc], 0, 0, 0);
            }
    }

    // bias + relu in place; track per-thread max
    float lmax = 0.f;
#pragma unroll
    for (int sr = 0; sr < 2; sr++)
#pragma unroll
        for (int sc = 0; sc < 8; sc++) {
            float bias = b2[n0 + sc * 16 + lr];
#pragma unroll
            for (int r = 0; r < 4; r++) {
                float v = fmaxf(acc[sr][sc][r] + bias, 0.f);
                acc[sr][sc][r] = v;
                lmax = fmaxf(lmax, v);
            }
        }
    // wave reduce then block reduce the tile max
#pragma unroll
    for (int ofs = 32; ofs > 0; ofs >>= 1)
        lmax = fmaxf(lmax, __shfl_xor(lmax, ofs));
    __shared__ float red[4];
    if (l == 0) red[w] = lmax;
    __syncthreads();
    float bmax = fmaxf(fmaxf(red[0], red[1]), fmaxf(red[2], red[3]));
    float inv = (bmax > 0.f) ? (65535.f / bmax) : 0.f;
    if (threadIdx.x == 0) g_scale[bid] = bmax * (1.f / 65535.f);

#pragma unroll
    for (int sr = 0; sr < 2; sr++)
#pragma unroll
        for (int sc = 0; sc < 8; sc++) {
            int col = n0 + sc * 16 + lr;
#pragma unroll
            for (int r = 0; r < 4; r++) {
                int row = m0 + sr * 16 + quad * 4 + r;
                u16 q = (u16)fminf(acc[sr][sc][r] * inv + 0.5f, 65535.f);
                Aq[(size_t)row * HH + col] = q;
            }
        }
}

// ---- per step: one wave per edge, msg = A_e @ x[src], scatter to m[tgt],m[src] ----
__global__ __launch_bounds__(256) void k_edge(const u16* __restrict__ Aq,
                                              const float* __restrict__ xcur,
                                              const int* __restrict__ edges,
                                              float* __restrict__ m) {
    int gid = blockIdx.x * 256 + threadIdx.x;
    int e = gid >> 6;
    int l = gid & 63;
    if (e >= N_EDGES) return;
    int src = edges[2 * e], tgt = edges[2 * e + 1];
    // row-tile of edge e = e>>7; lane l covers cols [0,64) -> col-tile 0..31? no:
    // A row = e's 64x64 matrix flattened: lane l owns matrix-row l, i.e. A-element
    // rows (e*64+l in GEMM M) — GEMM row = e*64+l? No: A[row=m][col] with
    // m = e (edge index in M=64000? M=64000 edges, each row is 4096 = 64x64).
    // GEMM M-index = e, columns 0..4095. Tile (rb,cb): rb = e>>7, cb = col>>7.
    // lane l reads cols [l*64, l*64+64): spans col-tile (l*64)>>7 = l>>1.
    float scale = g_scale[(e >> 7) * 32 + (l >> 1)];
    const uint4* arow = (const uint4*)(Aq + (size_t)e * HH + (size_t)l * HD);
    const float4* xs = (const float4*)(xcur + (size_t)src * HD);
    float acc = 0.f;
#pragma unroll
    for (int t = 0; t < 8; t++) {
        uint4 a = arow[t];
        float4 x0 = xs[2 * t];
        float4 x1 = xs[2 * t + 1];
        acc += (float)(a.x & 0xFFFFu) * x0.x + (float)(a.x >> 16) * x0.y;
        acc += (float)(a.y & 0xFFFFu) * x0.z + (float)(a.y >> 16) * x0.w;
        acc += (float)(a.z & 0xFFFFu) * x1.x + (float)(a.z >> 16) * x1.y;
        acc += (float)(a.w & 0xFFFFu) * x1.z + (float)(a.w >> 16) * x1.w;
    }
    float msg = acc * scale;
    unsafeAtomicAdd(&m[(size_t)tgt * HD + l], msg);
    if (src != tgt) unsafeAtomicAdd(&m[(size_t)src * HD + l], msg);
}

// ---- per step: GRU update per node; re-zero m for next step; fp32 out ----
__global__ __launch_bounds__(64) void k_gru(const float* __restrict__ xcur,
                                            float* __restrict__ m,
                                            const float* __restrict__ W_ih,
                                            const float* __restrict__ W_hh,
                                            const float* __restrict__ b_ih,
                                            const float* __restrict__ b_hh,
                                            float* __restrict__ xnext,
                                            float* __restrict__ out, int write_out) {
    int v = blockIdx.x, j = threadIdx.x;
    __shared__ float xs[HD], ms[HD];
    xs[j] = xcur[v * HD + j];
    ms[j] = m[v * HD + j];
    __syncthreads();
    float gir = b_ih[j], giz = b_ih[64 + j], gin = b_ih[128 + j];
    float ghr = b_hh[j], ghz = b_hh[64 + j], ghn = b_hh[128 + j];
    for (int k = 0; k < HD; k++) {
        float xk = xs[k], mk = ms[k];
        const float* wi_x = W_ih + k * 192;
        const float* wi_m = W_ih + (64 + k) * 192;
        const float* wh = W_hh + k * 192;
        gir += xk * wi_x[j] + mk * wi_m[j];
        giz += xk * wi_x[64 + j] + mk * wi_m[64 + j];
        gin += xk * wi_x[128 + j] + mk * wi_m[128 + j];
        ghr += xk * wh[j];
        ghz += xk * wh[64 + j];
        ghn += xk * wh[128 + j];
    }
    float r = 1.f / (1.f + __expf(-(gir + ghr)));
    float z = 1.f / (1.f + __expf(-(giz + ghz)));
    float n = tanhf(gin + r * ghn);
    float xn = (1.f - z) * n + z * xs[j];
    xnext[v * HD + j] = xn;
    m[v * HD + j] = 0.f;  // ready for next step's atomics
    if (write_out) out[v * HD + j] = xn;
}

extern "C" void kernel_launch(void* const* d_in, const int* in_sizes, int n_in,
                              void* d_out, int out_size, void* d_ws, size_t ws_size,
                              hipStream_t stream) {
    (void)in_sizes; (void)n_in; (void)out_size; (void)ws_size;
    const float* x_in      = (const float*)d_in[0];
    // d_in[1] adj: unused (zeros)
    const float* edge_data = (const float*)d_in[2];
    const int*   edges     = (const int*)d_in[3];
    // d_in[4] T: fixed at 8 (module constant in reference)
    const float* W1   = (const float*)d_in[5];
    const float* b1   = (const float*)d_in[6];
    const float* W2   = (const float*)d_in[7];
    const float* b2   = (const float*)d_in[8];
    const float* W_ih = (const float*)d_in[9];
    const float* W_hh = (const float*)d_in[10];
    const float* b_ih = (const float*)d_in[11];
    const float* b_hh = (const float*)d_in[12];
    float* out = (float*)d_out;

    // d_ws layout: Aq (524.3 MB) + x ping-pong + m (1.5 MB)  -> ~525.8 MB total
    char* ws = (char*)d_ws;
    u16* Aq = (u16*)ws;
    size_t off = (size_t)N_EDGES * HH * sizeof(u16);
    float* xb0 = (float*)(ws + off); off += (size_t)N_NODES * HD * sizeof(float);
    float* xb1 = (float*)(ws + off); off += (size_t)N_NODES * HD * sizeof(float);
    float* m   = (float*)(ws + off); off += (size_t)N_NODES * HD * sizeof(float);

    k_xinit<<<(N_NODES * HD + 255) / 256, 256, 0, stream>>>(x_in, xb0, m);
    k_h1<<<N_EDGES / 2, 256, 0, stream>>>(edge_data, edges, W1, b1);
    k_w2t<<<(HH * 128) / 256, 256, 0, stream>>>(W2);
    k_gemmA<<<(N_EDGES / 128) * (HH / 128), 256, 0, stream>>>(b2, Aq);

    float* bufs[2] = {xb0, xb1};
    for (int t = 0; t < T_STEPS; t++) {
        k_edge<<<(N_EDGES * 64) / 256, 256, 0, stream>>>(Aq, bufs[t & 1], edges, m);
        k_gru<<<N_NODES, 64, 0, stream>>>(bufs[t & 1], m, W_ih, W_hh, b_ih, b_hh,
                                          bufs[(t + 1) & 1], out,
                                          (t == T_STEPS - 1) ? 1 : 0);
    }
}

// Round 7
// 2249.624 us; speedup vs baseline: 1.0404x; 1.0404x over previous
//
#include <hip/hip_runtime.h>
#include <stdint.h>

#define N_NODES 2000
#define N_EDGES 64000
#define EDIM 16
#define ENH 128
#define HD 64
#define T_STEPS 8
#define HH 4096  // HD*HD

typedef unsigned short u16;
typedef __bf16 bf16x8 __attribute__((ext_vector_type(8)));
typedef float float4v __attribute__((ext_vector_type(4)));

// ---- static device scratch (rewritten every call); d_ws holds Aq + x/m ----
__device__ u16   g_h1_hi[(size_t)N_EDGES * ENH];   // 16.4 MB
__device__ u16   g_h1_lo[(size_t)N_EDGES * ENH];   // 16.4 MB
__device__ u16   g_w2t_hi[HH * ENH];               // 1 MB
__device__ u16   g_w2t_lo[HH * ENH];               // 1 MB
__device__ float g_scale[(N_EDGES / 16) * 32];     // per 16-edge x 128-n tile scale

__device__ __forceinline__ float b2f(u16 h) {
    union { unsigned int u; float f; } v; v.u = ((unsigned int)h) << 16; return v.f;
}
__device__ __forceinline__ u16 f2b(float f) {
    union { float f; unsigned int u; } v; v.f = f;
    unsigned int u = v.u;
    return (u16)((u + 0x7FFFu + ((u >> 16) & 1u)) >> 16);  // RNE
}

// ---- x fp32 -> ping-pong buffer; also zero m for the first step's atomics ----
__global__ void k_xinit(const float* __restrict__ xin, float* __restrict__ x0,
                        float* __restrict__ m) {
    int i = blockIdx.x * 256 + threadIdx.x;
    if (i < N_NODES * HD) { x0[i] = xin[i]; m[i] = 0.f; }
}

// ---- h1 = relu(ef @ W1 + b1) in fp32, stored as exact bf16 hi+lo split ----
__global__ __launch_bounds__(256) void k_h1(const float* __restrict__ edge_data,
                                            const int* __restrict__ edges,
                                            const float* __restrict__ W1,
                                            const float* __restrict__ b1) {
    int tid = threadIdx.x;
    int e = blockIdx.x * 2 + (tid >> 7);
    int c = tid & 127;
    int src = edges[2 * e], tgt = edges[2 * e + 1];
    const float* ef = edge_data + ((size_t)src * N_NODES + (size_t)tgt) * EDIM;
    float acc = b1[c];
#pragma unroll
    for (int k = 0; k < EDIM; k++)
        acc += ef[k] * W1[k * ENH + c];
    float v = fmaxf(acc, 0.f);
    u16 hi = f2b(v);
    size_t idx = (size_t)e * ENH + c;
    g_h1_hi[idx] = hi;
    g_h1_lo[idx] = f2b(v - b2f(hi));
}

// ---- W2 (128 x 4096) -> transposed bf16 hi/lo planes (k-contiguous) ----
__global__ void k_w2t(const float* __restrict__ W2) {
    int idx = blockIdx.x * 256 + threadIdx.x;  // = n*128 + k
    int n = idx >> 7, k = idx & 127;
    float v = W2[(size_t)k * HH + n];
    u16 hi = f2b(v);
    g_w2t_hi[idx] = hi;
    g_w2t_lo[idx] = f2b(v - b2f(hi));
}

// ---- A = relu(h1 @ W2 + b2) in ~fp32 via 3-way split MFMA; quantize per
// 16-edge x 128-n tile to u16. Block tile 64(M) x 128(N); wave = 16 x 128.
// Epilogue: LDS-staged coalesced dwordx4 stores. ----
__global__ __launch_bounds__(256) void k_gemmA(const float* __restrict__ b2,
                                               u16* __restrict__ Aq) {
    int bid = blockIdx.x;
    int cb = bid & 31;        // col-block fast: consecutive blocks share h1 tile
    int rb = bid >> 5;        // 0..999
    int w = threadIdx.x >> 6, l = threadIdx.x & 63;
    int quad = l >> 4, lr = l & 15;
    int m0 = rb * 64 + w * 16;   // 16 edges per wave
    int n0 = cb * 128;

    float4v acc[8];
#pragma unroll
    for (int j = 0; j < 8; j++) acc[j] = (float4v){0.f, 0.f, 0.f, 0.f};

#pragma unroll
    for (int kc = 0; kc < 4; kc++) {
        int ko = kc * 32 + quad * 8;
        size_t abase = (size_t)(m0 + lr) * 128 + ko;
        bf16x8 ah = *(const bf16x8*)(g_h1_hi + abase);
        bf16x8 al = *(const bf16x8*)(g_h1_lo + abase);
        bf16x8 bh[8], bl[8];
#pragma unroll
        for (int sc = 0; sc < 8; sc++) {
            size_t base = (size_t)(n0 + sc * 16 + lr) * 128 + ko;
            bh[sc] = *(const bf16x8*)(g_w2t_hi + base);
            bl[sc] = *(const bf16x8*)(g_w2t_lo + base);
        }
#pragma unroll
        for (int sc = 0; sc < 8; sc++) {
            acc[sc] = __builtin_amdgcn_mfma_f32_16x16x32_bf16(ah, bh[sc], acc[sc], 0, 0, 0);
            acc[sc] = __builtin_amdgcn_mfma_f32_16x16x32_bf16(ah, bl[sc], acc[sc], 0, 0, 0);
            acc[sc] = __builtin_amdgcn_mfma_f32_16x16x32_bf16(al, bh[sc], acc[sc], 0, 0, 0);
        }
    }

    // bias + relu in place; per-wave (16-edge x 128-n tile) max
    float lmax = 0.f;
#pragma unroll
    for (int sc = 0; sc < 8; sc++) {
        float bias = b2[n0 + sc * 16 + lr];
#pragma unroll
        for (int r = 0; r < 4; r++) {
            float v = fmaxf(acc[sc][r] + bias, 0.f);
            acc[sc][r] = v;
            lmax = fmaxf(lmax, v);
        }
    }
#pragma unroll
    for (int ofs = 32; ofs > 0; ofs >>= 1)
        lmax = fmaxf(lmax, __shfl_xor(lmax, ofs));
    float inv = (lmax > 0.f) ? (65535.f / lmax) : 0.f;
    if (l == 0) g_scale[(m0 >> 4) * 32 + cb] = lmax * (1.f / 65535.f);

    // quantize into LDS (row-major 16x128 per wave), then coalesced stores
    __shared__ u16 st[4][16][128];
#pragma unroll
    for (int sc = 0; sc < 8; sc++) {
        int col = sc * 16 + lr;
#pragma unroll
        for (int r = 0; r < 4; r++) {
            u16 q = (u16)fminf(acc[sc][r] * inv + 0.5f, 65535.f);
            st[w][quad * 4 + r][col] = q;
        }
    }
    __syncthreads();
#pragma unroll
    for (int i = 0; i < 4; i++) {
        int el = i * 4 + (l >> 4);     // edge-local 0..15
        int chunk = l & 15;            // 16B chunk within the 256B row
        uint4 v = *(const uint4*)&st[w][el][chunk * 8];
        *(uint4*)(Aq + (size_t)(m0 + el) * HH + n0 + chunk * 8) = v;
    }
}

// ---- per step: one wave per edge, fully-coalesced Aq reads + 8-lane
// butterfly reduction. msg = A_e @ x[src], scatter to m[tgt], m[src]. ----
__global__ __launch_bounds__(256) void k_edge(const u16* __restrict__ Aq,
                                              const float* __restrict__ xcur,
                                              const int* __restrict__ edges,
                                              float* __restrict__ m) {
    int gid = blockIdx.x * 256 + threadIdx.x;
    int e = gid >> 6;
    int l = gid & 63;
    int src = edges[2 * e], tgt = edges[2 * e + 1];
    // lane l's x chunk: cols [(l&7)*8, +8) — invariant across t
    const float4* xp = (const float4*)(xcur + (size_t)src * HD + (l & 7) * 8);
    float4 xa = xp[0], xb = xp[1];
    const uint4* ap = (const uint4*)(Aq + (size_t)e * HH);  // 8KB row-major edge matrix
    float msgv = 0.f;
#pragma unroll
    for (int t = 0; t < 8; t++) {
        // lane l loads flat u16 [t*512 + l*8, +8): row 8t+(l>>3), cols (l&7)*8..+8
        // uint4 index = (t*512 + l*8)/8 = t*64 + l   (uint4 = 8 u16!)
        uint4 a = ap[t * 64 + l];
        float p;
        p  = (float)(a.x & 0xFFFFu) * xa.x + (float)(a.x >> 16) * xa.y;
        p += (float)(a.y & 0xFFFFu) * xa.z + (float)(a.y >> 16) * xa.w;
        p += (float)(a.z & 0xFFFFu) * xb.x + (float)(a.z >> 16) * xb.y;
        p += (float)(a.w & 0xFFFFu) * xb.z + (float)(a.w >> 16) * xb.w;
        // reduce over the 8 lanes sharing this row (same l>>3)
        p += __shfl_xor(p, 1);
        p += __shfl_xor(p, 2);
        p += __shfl_xor(p, 4);
        msgv = ((l & 7) == t) ? p : msgv;
    }
    int r = (l & 7) * 8 + (l >> 3);  // row this lane ended up owning (bijection)
    float scale = g_scale[(e >> 4) * 32 + (r >> 1)];
    float msg = msgv * scale;
    unsafeAtomicAdd(&m[(size_t)tgt * HD + r], msg);
    if (src != tgt) unsafeAtomicAdd(&m[(size_t)src * HD + r], msg);
}

// ---- per step: GRU update per node; re-zero m for next step; fp32 out ----
__global__ __launch_bounds__(64) void k_gru(const float* __restrict__ xcur,
                                            float* __restrict__ m,
                                            const float* __restrict__ W_ih,
                                            const float* __restrict__ W_hh,
                                            const float* __restrict__ b_ih,
                                            const float* __restrict__ b_hh,
                                            float* __restrict__ xnext,
                                            float* __restrict__ out, int write_out) {
    int v = blockIdx.x, j = threadIdx.x;
    __shared__ float xs[HD], ms[HD];
    xs[j] = xcur[v * HD + j];
    ms[j] = m[v * HD + j];
    __syncthreads();
    float gir = b_ih[j], giz = b_ih[64 + j], gin = b_ih[128 + j];
    float ghr = b_hh[j], ghz = b_hh[64 + j], ghn = b_hh[128 + j];
    for (int k = 0; k < HD; k++) {
        float xk = xs[k], mk = ms[k];
        const float* wi_x = W_ih + k * 192;
        const float* wi_m = W_ih + (64 + k) * 192;
        const float* wh = W_hh + k * 192;
        gir += xk * wi_x[j] + mk * wi_m[j];
        giz += xk * wi_x[64 + j] + mk * wi_m[64 + j];
        gin += xk * wi_x[128 + j] + mk * wi_m[128 + j];
        ghr += xk * wh[j];
        ghz += xk * wh[64 + j];
        ghn += xk * wh[128 + j];
    }
    float r = 1.f / (1.f + __expf(-(gir + ghr)));
    float z = 1.f / (1.f + __expf(-(giz + ghz)));
    float n = tanhf(gin + r * ghn);
    float xn = (1.f - z) * n + z * xs[j];
    xnext[v * HD + j] = xn;
    m[v * HD + j] = 0.f;  // ready for next step's atomics
    if (write_out) out[v * HD + j] = xn;
}

extern "C" void kernel_launch(void* const* d_in, const int* in_sizes, int n_in,
                              void* d_out, int out_size, void* d_ws, size_t ws_size,
                              hipStream_t stream) {
    (void)in_sizes; (void)n_in; (void)out_size; (void)ws_size;
    const float* x_in      = (const float*)d_in[0];
    // d_in[1] adj: unused (zeros)
    const float* edge_data = (const float*)d_in[2];
    const int*   edges     = (const int*)d_in[3];
    // d_in[4] T: fixed at 8 (module constant in reference)
    const float* W1   = (const float*)d_in[5];
    const float* b1   = (const float*)d_in[6];
    const float* W2   = (const float*)d_in[7];
    const float* b2   = (const float*)d_in[8];
    const float* W_ih = (const float*)d_in[9];
    const float* W_hh = (const float*)d_in[10];
    const float* b_ih = (const float*)d_in[11];
    const float* b_hh = (const float*)d_in[12];
    float* out = (float*)d_out;

    // d_ws layout: Aq (524.3 MB) + x ping-pong + m (1.5 MB)
    char* ws = (char*)d_ws;
    u16* Aq = (u16*)ws;
    size_t off = (size_t)N_EDGES * HH * sizeof(u16);
    float* xb0 = (float*)(ws + off); off += (size_t)N_NODES * HD * sizeof(float);
    float* xb1 = (float*)(ws + off); off += (size_t)N_NODES * HD * sizeof(float);
    float* m   = (float*)(ws + off); off += (size_t)N_NODES * HD * sizeof(float);

    k_xinit<<<(N_NODES * HD + 255) / 256, 256, 0, stream>>>(x_in, xb0, m);
    k_h1<<<N_EDGES / 2, 256, 0, stream>>>(edge_data, edges, W1, b1);
    k_w2t<<<(HH * 128) / 256, 256, 0, stream>>>(W2);
    k_gemmA<<<(N_EDGES / 64) * (HH / 128), 256, 0, stream>>>(b2, Aq);

    float* bufs[2] = {xb0, xb1};
    for (int t = 0; t < T_STEPS; t++) {
        k_edge<<<(N_EDGES * 64) / 256, 256, 0, stream>>>(Aq, bufs[t & 1], edges, m);
        k_gru<<<N_NODES, 64, 0, stream>>>(bufs[t & 1], m, W_ih, W_hh, b_ih, b_hh,
                                          bufs[(t + 1) & 1], out,
                                          (t == T_STEPS - 1) ? 1 : 0);
    }
}